// Round 2
// baseline (705.792 us; speedup 1.0000x reference)
//
#include <hip/hip_runtime.h>
#include <stdint.h>
#include <math.h>

#define WIDTH  1024
#define HEIGHT 1024
#define DDIM   128
#define TOPK   2048
#define CAP    131072     // > 1024*1024/9 strict 5x5 maxima bound
#define SELCAP 4096       // superset capacity: 2048 + threshold-bin (~300 expected)

// ---- workspace layout (bytes from d_ws) -----------------------------------
// hdr[0] = candidate count (only header word still needed after fusion)
#define HIST_OFF 64
#define KEYS_OFF (HIST_OFF + 65536 * 4)          // 262208
#define SIDX_OFF (KEYS_OFF + CAP * 8)            // +1 MiB; total ~1.32 MiB

// ---------------------------------------------------------------------------
// Kernel 1: 5x5 NMS via clamped (=clipped, duplicates don't change max) reads,
// 3x3 early exit. Per-row block: LDS candidate buffer -> ONE global atomic per
// block. Also builds 65536-bin histogram of key top-16 bits (sign+exp+7 mant).
// key = (score_bits<<32) | ~idx : monotone for score>0, ties -> ascending idx.
// ---------------------------------------------------------------------------
__global__ __launch_bounds__(1024) void find_candidates(
        const float* __restrict__ feat,
        const int* __restrict__ p_ow, const int* __restrict__ p_oh,
        unsigned int* __restrict__ hdr,
        unsigned int* __restrict__ hist,
        unsigned long long* __restrict__ keys) {
    const int x = threadIdx.x;
    const int y = blockIdx.x;
    const float* hm = feat + (size_t)DDIM * WIDTH * HEIGHT;

    __shared__ unsigned long long lkeys[256];
    __shared__ unsigned int lcnt, lbase;
    if (x == 0) lcnt = 0u;
    __syncthreads();

    float c = hm[y * WIDTH + x];
    // heatmap > 0 (rejects NaN too) & in_bounds
    if ((c > 0.0f) && (x <= p_ow[0] - 1) && (y <= p_oh[0] - 1)) {
        int xm2 = max(x - 2, 0), xm1 = max(x - 1, 0);
        int xp1 = min(x + 1, WIDTH - 1), xp2 = min(x + 2, WIDTH - 1);
        int ym2 = max(y - 2, 0), ym1 = max(y - 1, 0);
        int yp1 = min(y + 1, HEIGHT - 1), yp2 = min(y + 2, HEIGHT - 1);
        const float* r0 = hm + ym1 * WIDTH;
        const float* r1 = hm + y   * WIDTH;
        const float* r2 = hm + yp1 * WIDTH;
        // inner 3x3 ring first (8 loads) — rejects ~8/9 of positives
        float m = fmaxf(fmaxf(fmaxf(r0[xm1], r0[x]), fmaxf(r0[xp1], r1[xm1])),
                        fmaxf(fmaxf(r1[xp1], r2[xm1]), fmaxf(r2[x], r2[xp1])));
        if (m <= c) {
            const float* ra = hm + ym2 * WIDTH;
            const float* rb = hm + yp2 * WIDTH;
            float m2 = fmaxf(fmaxf(fmaxf(ra[xm2], ra[xm1]), fmaxf(ra[x], ra[xp1])), ra[xp2]);
            m2 = fmaxf(m2, fmaxf(fmaxf(rb[xm2], rb[xm1]), fmaxf(fmaxf(rb[x], rb[xp1]), rb[xp2])));
            m2 = fmaxf(m2, fmaxf(fmaxf(r0[xm2], r0[xp2]), fmaxf(r1[xm2], r1[xp2])));
            m2 = fmaxf(m2, fmaxf(r2[xm2], r2[xp2]));
            if (m2 <= c) {   // strict local max of clipped 5x5 window
                unsigned int idx = (unsigned int)(y * WIDTH + x);
                unsigned long long key =
                    ((unsigned long long)__float_as_uint(c) << 32) |
                    (unsigned long long)(~idx);
                unsigned int p = atomicAdd(&lcnt, 1u);
                if (p < 256u) lkeys[p] = key;
            }
        }
    }
    __syncthreads();
    if (x == 0) lbase = atomicAdd(&hdr[0], lcnt);
    __syncthreads();
    unsigned int n = lcnt < 256u ? lcnt : 256u;
    unsigned int base = lbase;
    for (unsigned int i = x; i < n; i += blockDim.x) {
        unsigned long long k = lkeys[i];
        if (base + i < CAP) keys[base + i] = k;
        atomicAdd(&hist[(unsigned int)(k >> 48)], 1u);
    }
}

// ---------------------------------------------------------------------------
// Kernel 2 (fused scan_hist + filter_keys + sort_emit): ONE block.
//  phase 1: parallel suffix-scan of the 65536-bin histogram -> threshold bin
//           B such that count(bins > B) < target <= count(bins >= B), with
//           target = min(N, TOPK).
//  phase 2: filter keys with top16 >= B straight into LDS (superset of the
//           exact top-K, ~2.3K keys; no global sel round-trip, no hdr[1..3]).
//  phase 3: bitonic sort SELCAP keys (0-padded) descending in LDS.
//  phase 4: emit exact top-TOPK: keypoints, scores, valid, idx list.
// ---------------------------------------------------------------------------
__global__ __launch_bounds__(1024) void select_emit(
        const unsigned int* __restrict__ hdr,
        const unsigned int* __restrict__ hist,
        const unsigned long long* __restrict__ keys,
        float* __restrict__ out_kp, float* __restrict__ out_sc,
        float* __restrict__ out_vd, unsigned int* __restrict__ sidx) {
    __shared__ unsigned long long sk[SELCAP];   // 32 KiB
    __shared__ unsigned int part[1024];         // 4 KiB
    __shared__ unsigned int scnt;
    __shared__ unsigned int sB;
    const int tid = threadIdx.x;

    // ---- phase 1: suffix-scan histogram -> threshold bin ----
    const unsigned int base = (unsigned int)tid * 64u;
    unsigned int s = 0;
    #pragma unroll 8
    for (int j = 0; j < 64; ++j) s += hist[base + j];
    part[tid] = s;
    if (tid == 0) { scnt = 0u; sB = 0u; }
    __syncthreads();
    // inclusive suffix sums: part[t] = sum_{t' >= t} partial[t']
    for (int d = 1; d < 1024; d <<= 1) {
        unsigned int v = (tid + d < 1024) ? part[tid + d] : 0u;
        __syncthreads();
        part[tid] += v;
        __syncthreads();
    }
    unsigned int N = hdr[0]; if (N > CAP) N = CAP;
    const unsigned int target = N < TOPK ? N : TOPK;
    if (target != 0) {
        unsigned int St = part[tid];
        unsigned int Sn = (tid < 1023) ? part[tid + 1] : 0u;
        if (St >= target && Sn < target) {      // exactly one thread
            unsigned int above = Sn;
            unsigned int B = base;
            for (int b = (int)base + 63; b >= (int)base; --b) {
                unsigned int h = hist[b];
                if (above + h >= target) { B = (unsigned int)b; break; }
                above += h;
            }
            sB = B;
        }
    }
    // zero-pad LDS key buffer (valid keys have score>0 -> key >= 2^32 > 0)
    for (unsigned int i = tid; i < SELCAP; i += 1024) sk[i] = 0ull;
    __syncthreads();

    // ---- phase 2: filter keys >= bin B into LDS ----
    const unsigned long long B = (unsigned long long)sB;
    for (unsigned int i = tid; i < N; i += 1024) {
        unsigned long long k = keys[i];
        if ((k >> 48) >= B) {
            unsigned int p = atomicAdd(&scnt, 1u);
            if (p < SELCAP) sk[p] = k;
        }
    }
    __syncthreads();

    // ---- phase 3: bitonic sort descending ----
    for (unsigned int size = 2; size <= SELCAP; size <<= 1) {
        for (unsigned int str = size >> 1; str > 0; str >>= 1) {
            for (unsigned int i = tid; i < SELCAP; i += 1024) {
                unsigned int j = i ^ str;
                if (j > i) {
                    unsigned long long a = sk[i], b = sk[j];
                    bool desc = ((i & size) == 0);
                    if (desc ? (a < b) : (a > b)) { sk[i] = b; sk[j] = a; }
                }
            }
            __syncthreads();
        }
    }

    // ---- phase 4: emit exact top-TOPK ----
    for (unsigned int r = tid; r < TOPK; r += 1024) {
        unsigned long long k = sk[r];
        bool live = (r < target);
        unsigned int idx = ~(unsigned int)(k & 0xFFFFFFFFull);
        out_kp[2 * r + 0] = live ? (float)(idx & (WIDTH - 1)) : 0.0f;
        out_kp[2 * r + 1] = live ? (float)(idx >> 10) : 0.0f;
        out_sc[r] = live ? __uint_as_float((unsigned int)(k >> 32)) : -INFINITY;
        out_vd[r] = live ? 1.0f : 0.0f;
        sidx[r]   = live ? idx : 0u;
    }
}

// ---------------------------------------------------------------------------
// Kernel 3: descriptor gather + L2 normalize. ONE WAVE per keypoint, 2
// channels/lane, __shfl_xor butterfly reduce — no LDS, no __syncthreads.
// 4 keypoints per 256-thread block.
// ---------------------------------------------------------------------------
__global__ __launch_bounds__(256) void gather_desc(
        const float* __restrict__ feat,
        const unsigned int* __restrict__ sidx,
        float* __restrict__ out_d) {
    const int lane = threadIdx.x & 63;
    const int kp   = blockIdx.x * 4 + (threadIdx.x >> 6);
    const unsigned int idx = sidx[kp];
    const float* p = feat + idx;
    float v0 = p[(size_t)lane        * (WIDTH * HEIGHT)];
    float v1 = p[(size_t)(lane + 64) * (WIDTH * HEIGHT)];
    float s = v0 * v0 + v1 * v1;
    #pragma unroll
    for (int off = 32; off > 0; off >>= 1) s += __shfl_xor(s, off, 64);
    float inv = 1.0f / fmaxf(sqrtf(s), 1e-12f);
    out_d[(size_t)kp * DDIM + lane]      = v0 * inv;
    out_d[(size_t)kp * DDIM + 64 + lane] = v1 * inv;
}

// ---------------------------------------------------------------------------
extern "C" void kernel_launch(void* const* d_in, const int* in_sizes, int n_in,
                              void* d_out, int out_size, void* d_ws, size_t ws_size,
                              hipStream_t stream) {
    const float* feat = (const float*)d_in[0];
    const int* p_ow = (const int*)d_in[1];
    const int* p_oh = (const int*)d_in[2];
    // d_in[3]=max_keypoints(2048), d_in[4]=window(5): baked into TOPK / radius 2.

    float* out = (float*)d_out;
    float* out_kp = out;                              // 2048*2
    float* out_sc = out + 2 * TOPK;                   // 2048
    float* out_d  = out + 3 * TOPK;                   // 2048*128
    float* out_vd = out + 3 * TOPK + TOPK * DDIM;     // 2048

    unsigned int* hdr  = (unsigned int*)d_ws;
    unsigned int* hist = (unsigned int*)((char*)d_ws + HIST_OFF);
    unsigned long long* keys = (unsigned long long*)((char*)d_ws + KEYS_OFF);
    unsigned int* sidx = (unsigned int*)((char*)d_ws + SIDX_OFF);

    hipMemsetAsync(d_ws, 0, KEYS_OFF, stream);        // hdr + 256 KiB histogram

    find_candidates<<<HEIGHT, 1024, 0, stream>>>(feat, p_ow, p_oh, hdr, hist, keys);
    select_emit<<<1, 1024, 0, stream>>>(hdr, hist, keys, out_kp, out_sc, out_vd, sidx);
    gather_desc<<<TOPK / 4, 256, 0, stream>>>(feat, sidx, out_d);
}